// Round 20
// baseline (503.726 us; speedup 1.0000x reference)
//
#include <hip/hip_runtime.h>
#include <hip/hip_bf16.h>
#include <hip/amd_detail/amd_hip_unsafe_atomics.h>

#define N_EDGES 200000
#define N_NODES 20000
#define N_GRAPHS 128
#define IN_DIM 16
#define EDGE_DIM 8
#define HID 64
#define OUT_DIM 10
#define SCAN_NBLK ((N_NODES + 1023) / 1024)   // 20
#define N_TILES (N_EDGES / 16)                // 12500 tiles of 16 edges
#define TPW 1                                 // tiles per wave (R19: 2->1 for occupancy)
#define N_EWAVES (N_TILES / TPW)              // 12500

typedef __attribute__((ext_vector_type(8))) short bf16x8;
typedef __attribute__((ext_vector_type(4))) float f32x4;

__device__ __forceinline__ ushort f2bf(float x) {
    unsigned b = __float_as_uint(x);
    return (ushort)((b + 0x7FFFu + ((b >> 16) & 1u)) >> 16);
}
__device__ __forceinline__ float bf2f(ushort u) {
    return __uint_as_float(((unsigned)u) << 16);
}

// ---------------------------------------------------------------------------
// Kernel A (combo): blocks 0..15  = precompute W3p/b3p/r,
//                   blocks 16..63 = pack w1,w2 into MFMA B-frag bf16 hi/lo,
//                   blocks 64..   = histogram of dst.
// ---------------------------------------------------------------------------
__global__ __launch_bounds__(256) void combo_kernel(
    const float* __restrict__ emb, const float* __restrict__ w3,
    const float* __restrict__ b3, const float* __restrict__ root_w,
    const float* __restrict__ conv_b, const int* __restrict__ dst_idx,
    const float* __restrict__ w1, const float* __restrict__ w2,
    float* __restrict__ W3p, float* __restrict__ b3p, float* __restrict__ r,
    ushort* __restrict__ fw1, ushort* __restrict__ fw2,
    int* __restrict__ counts)
{
    if (blockIdx.x < 16) {
        int t = blockIdx.x * 256 + threadIdx.x;   // 0..4095
        int k = t >> 6;
        int h = t & 63;
        float acc = 0.f;
#pragma unroll
        for (int i = 0; i < IN_DIM; ++i)
            acc = fmaf(emb[i], w3[k * (IN_DIM * HID) + i * HID + h], acc);
        W3p[t] = acc;
        if (t < HID) {
            float a = 0.f, rr = 0.f;
#pragma unroll
            for (int i = 0; i < IN_DIM; ++i) {
                a  = fmaf(emb[i], b3[i * HID + t], a);
                rr = fmaf(emb[i], root_w[i * HID + t], rr);
            }
            b3p[t] = a;
            r[t]   = rr + conv_b[t];
        }
    } else if (blockIdx.x < 64) {
        int idx  = (blockIdx.x - 16) * 256 + threadIdx.x;  // 0..12287
        int frag = idx >> 9;
        int rem  = idx & 511;
        int lane = rem >> 3, i = rem & 7;
        int q = lane >> 4, n16 = lane & 15;
        if (frag < 8) {
            int t = frag >> 1, h = frag & 1;
            int k = 8 * q + i, n = t * 16 + n16;
            float v = (k < EDGE_DIM) ? w1[k * HID + n] : 0.f;
            ushort hi = f2bf(v);
            fw1[((t * 2 + h) * 64 + lane) * 8 + i] =
                (h == 0) ? hi : f2bf(v - bf2f(hi));
        } else {
            int u = frag - 8;
            int t = u >> 2, f = (u >> 1) & 1, h = u & 1;
            int k = f * 32 + 8 * q + i, n = t * 16 + n16;
            float v = w2[k * HID + n];
            ushort hi = f2bf(v);
            fw2[(((t * 2 + f) * 2 + h) * 64 + lane) * 8 + i] =
                (h == 0) ? hi : f2bf(v - bf2f(hi));
        }
    } else {
        int e = (blockIdx.x - 64) * 256 + threadIdx.x;
        if (e < N_EDGES) atomicAdd(&counts[dst_idx[e]], 1);
    }
}

// ---------------------------------------------------------------------------
// scanA: block-local scan (+ extra blocks pack W3p frags).
// ---------------------------------------------------------------------------
__global__ __launch_bounds__(1024) void scanA_kernel(
    const int* __restrict__ counts, int* __restrict__ start, int* __restrict__ tot,
    const float* __restrict__ W3p, ushort* __restrict__ fw3)
{
    const int b = blockIdx.x, t = threadIdx.x;
    if (b >= SCAN_NBLK) {                       // blocks 20..27: fw3 prep
        int idx  = (b - SCAN_NBLK) * 1024 + t;  // 0..8191
        int u    = idx >> 9;
        int rem  = idx & 511;
        int lane = rem >> 3, i = rem & 7;
        int tt = u >> 2, f = (u >> 1) & 1, h = u & 1;
        int k = f * 32 + 8 * (lane >> 4) + i, n = tt * 16 + (lane & 15);
        float v = W3p[k * HID + n];
        ushort hi = f2bf(v);
        fw3[(((tt * 2 + f) * 2 + h) * 64 + lane) * 8 + i] =
            (h == 0) ? hi : f2bf(v - bf2f(hi));
        return;
    }
    const int i = b * 1024 + t;
    const int v = (i < N_NODES) ? counts[i] : 0;
    const int lane = t & 63, wid = t >> 6;
    __shared__ int wsum[16];
    int incl = v;
#pragma unroll
    for (int off = 1; off < 64; off <<= 1) {
        int u = __shfl_up(incl, off, 64);
        if (lane >= off) incl += u;
    }
    if (lane == 63) wsum[wid] = incl;
    __syncthreads();
    if (wid == 0) {
        int wv = (lane < 16) ? wsum[lane] : 0;
        int wi = wv;
#pragma unroll
        for (int off = 1; off < 16; off <<= 1) {
            int u = __shfl_up(wi, off, 64);
            if (lane >= off) wi += u;
        }
        if (lane < 16) wsum[lane] = wi - wv;
    }
    __syncthreads();
    const int excl = wsum[wid] + incl - v;
    if (i < N_NODES) start[i] = excl;
    if (t == 1023) tot[b] = excl + v;
}

// ---------------------------------------------------------------------------
// scanC: block b sums tot[0..b-1] with a wave reduce, then applies offset.
// ---------------------------------------------------------------------------
__global__ __launch_bounds__(1024) void scanC_kernel(
    int* __restrict__ start, int* __restrict__ cursor, const int* __restrict__ tot)
{
    __shared__ int s_off;
    const int b = blockIdx.x, t = threadIdx.x;
    if (t < 64) {
        int v = (t < b && t < SCAN_NBLK) ? tot[t] : 0;
#pragma unroll
        for (int o = 32; o >= 1; o >>= 1) v += __shfl_xor(v, o, 64);
        if (t == 0) s_off = v;
    }
    __syncthreads();
    const int i = b * 1024 + t;
    if (i < N_NODES) {
        const int s = start[i] + s_off;
        start[i]  = s;
        cursor[i] = s;
    }
    if (b == 0 && t == 0) start[N_NODES] = N_EDGES;
}

// ---------------------------------------------------------------------------
// Kernel D: edge MLP on matrix cores, split-bf16 (verified: absmax 3e-5).
// TPW=1: 18.4 KB LDS/block -> 8 blocks/CU for latency hiding.
// ---------------------------------------------------------------------------
__global__ __launch_bounds__(256) void edge_mfma_kernel(
    const float* __restrict__ edge_attr, const int* __restrict__ dst_idx,
    const ushort* __restrict__ fw1, const ushort* __restrict__ fw2,
    const ushort* __restrict__ fw3,
    const float* __restrict__ b1, const float* __restrict__ b2,
    const float* __restrict__ b3p,
    int* __restrict__ cursor, ushort* __restrict__ msg16)
{
    const int lane = threadIdx.x & 63;
    const int wv   = threadIdx.x >> 6;
    const int gw   = blockIdx.x * 4 + wv;
    const int tile0 = gw * TPW;
    if (tile0 >= N_TILES) return;
    const int q = lane >> 4, l16 = lane & 15;

    __shared__ ushort s_hi[4][TPW][16][72];
    __shared__ ushort s_lo[4][TPW][16][72];

    float bb1[4], bb2[4], bb3[4];
#pragma unroll
    for (int t = 0; t < 4; ++t) {
        bb1[t] = b1[t * 16 + l16];
        bb2[t] = b2[t * 16 + l16];
        bb3[t] = b3p[t * 16 + l16];
    }

    float e8[TPW][8];
    int   p_mine[TPW];
#pragma unroll
    for (int tt = 0; tt < TPW; ++tt) {
        p_mine[tt] = 0;
#pragma unroll
        for (int i = 0; i < 8; ++i) e8[tt][i] = 0.f;
        if (lane < 16) {
            const long em = (long)(tile0 + tt) * 16 + lane;
            const float4 A = *(const float4*)&edge_attr[em * EDGE_DIM + 0];
            const float4 B = *(const float4*)&edge_attr[em * EDGE_DIM + 4];
            e8[tt][0] = A.x; e8[tt][1] = A.y; e8[tt][2] = A.z; e8[tt][3] = A.w;
            e8[tt][4] = B.x; e8[tt][5] = B.y; e8[tt][6] = B.z; e8[tt][7] = B.w;
            p_mine[tt] = atomicAdd(&cursor[dst_idx[em]], 1);
        }
    }

    // ---- phase 1: L1 (K=8 zero-padded) ----
    {
        bf16x8 w1h[4], w1l[4];
#pragma unroll
        for (int t = 0; t < 4; ++t) {
            w1h[t] = ((const bf16x8*)fw1)[(t * 2 + 0) * 64 + lane];
            w1l[t] = ((const bf16x8*)fw1)[(t * 2 + 1) * 64 + lane];
        }
#pragma unroll
        for (int tt = 0; tt < TPW; ++tt) {
            bf16x8 a1h, a1l;
#pragma unroll
            for (int i = 0; i < 8; ++i) {
                const ushort hi = f2bf(e8[tt][i]);
                a1h[i] = (short)hi;
                a1l[i] = (short)f2bf(e8[tt][i] - bf2f(hi));
            }
#pragma unroll
            for (int t = 0; t < 4; ++t) {
                f32x4 c = {0.f, 0.f, 0.f, 0.f};
                c = __builtin_amdgcn_mfma_f32_16x16x32_bf16(a1l, w1h[t], c, 0, 0, 0);
                c = __builtin_amdgcn_mfma_f32_16x16x32_bf16(a1h, w1l[t], c, 0, 0, 0);
                c = __builtin_amdgcn_mfma_f32_16x16x32_bf16(a1h, w1h[t], c, 0, 0, 0);
#pragma unroll
                for (int rr = 0; rr < 4; ++rr) {
                    float x = fmaxf(c[rr] + bb1[t], 0.f);
                    const ushort hi = f2bf(x);
                    s_hi[wv][tt][q * 4 + rr][t * 16 + l16] = hi;
                    s_lo[wv][tt][q * 4 + rr][t * 16 + l16] = f2bf(x - bf2f(hi));
                }
            }
        }
    }

    // ---- phase 2: L2 (K=64) ----
    {
        bf16x8 w2h[4][2], w2l[4][2];
#pragma unroll
        for (int t = 0; t < 4; ++t)
#pragma unroll
            for (int f = 0; f < 2; ++f) {
                w2h[t][f] = ((const bf16x8*)fw2)[((t * 2 + f) * 2 + 0) * 64 + lane];
                w2l[t][f] = ((const bf16x8*)fw2)[((t * 2 + f) * 2 + 1) * 64 + lane];
            }
#pragma unroll
        for (int tt = 0; tt < TPW; ++tt) {
            bf16x8 a2h[2], a2l[2];
#pragma unroll
            for (int f = 0; f < 2; ++f) {
                a2h[f] = *(const bf16x8*)&s_hi[wv][tt][l16][f * 32 + 8 * q];
                a2l[f] = *(const bf16x8*)&s_lo[wv][tt][l16][f * 32 + 8 * q];
            }
            f32x4 cc[4];
#pragma unroll
            for (int t = 0; t < 4; ++t) {
                f32x4 c = {0.f, 0.f, 0.f, 0.f};
#pragma unroll
                for (int f = 0; f < 2; ++f) {
                    c = __builtin_amdgcn_mfma_f32_16x16x32_bf16(a2l[f], w2h[t][f], c, 0, 0, 0);
                    c = __builtin_amdgcn_mfma_f32_16x16x32_bf16(a2h[f], w2l[t][f], c, 0, 0, 0);
                    c = __builtin_amdgcn_mfma_f32_16x16x32_bf16(a2h[f], w2h[t][f], c, 0, 0, 0);
                }
                cc[t] = c;
            }
#pragma unroll
            for (int t = 0; t < 4; ++t)
#pragma unroll
                for (int rr = 0; rr < 4; ++rr) {
                    float x = fmaxf(cc[t][rr] + bb2[t], 0.f);
                    const ushort hi = f2bf(x);
                    s_hi[wv][tt][q * 4 + rr][t * 16 + l16] = hi;
                    s_lo[wv][tt][q * 4 + rr][t * 16 + l16] = f2bf(x - bf2f(hi));
                }
        }
    }

    // ---- phase 3: L3 (K=64) + bf16 store ----
    {
        bf16x8 w3h[4][2], w3l[4][2];
#pragma unroll
        for (int t = 0; t < 4; ++t)
#pragma unroll
            for (int f = 0; f < 2; ++f) {
                w3h[t][f] = ((const bf16x8*)fw3)[((t * 2 + f) * 2 + 0) * 64 + lane];
                w3l[t][f] = ((const bf16x8*)fw3)[((t * 2 + f) * 2 + 1) * 64 + lane];
            }
#pragma unroll
        for (int tt = 0; tt < TPW; ++tt) {
            bf16x8 a3h[2], a3l[2];
#pragma unroll
            for (int f = 0; f < 2; ++f) {
                a3h[f] = *(const bf16x8*)&s_hi[wv][tt][l16][f * 32 + 8 * q];
                a3l[f] = *(const bf16x8*)&s_lo[wv][tt][l16][f * 32 + 8 * q];
            }
            f32x4 cc[4];
#pragma unroll
            for (int t = 0; t < 4; ++t) {
                f32x4 c = {0.f, 0.f, 0.f, 0.f};
#pragma unroll
                for (int f = 0; f < 2; ++f) {
                    c = __builtin_amdgcn_mfma_f32_16x16x32_bf16(a3l[f], w3h[t][f], c, 0, 0, 0);
                    c = __builtin_amdgcn_mfma_f32_16x16x32_bf16(a3h[f], w3l[t][f], c, 0, 0, 0);
                    c = __builtin_amdgcn_mfma_f32_16x16x32_bf16(a3h[f], w3h[t][f], c, 0, 0, 0);
                }
                cc[t] = c;
            }
            int p_r[4];
#pragma unroll
            for (int rr = 0; rr < 4; ++rr)
                p_r[rr] = __shfl(p_mine[tt], q * 4 + rr);
#pragma unroll
            for (int t = 0; t < 4; ++t)
#pragma unroll
                for (int rr = 0; rr < 4; ++rr)
                    msg16[(long)p_r[rr] * HID + t * 16 + l16] =
                        f2bf(cc[t][rr] + bb3[t]);
        }
    }
}

// ---------------------------------------------------------------------------
// Kernel E: gather + fused head. Gather: GN_PER_WAVE=8 (measured best),
// 2-way pipelined p-loop. After all blocks finish (agent-scope done counter),
// the LAST block computes the classifier head (2 graphs in parallel).
// ---------------------------------------------------------------------------
#define GN_PER_WAVE 8
__global__ __launch_bounds__(256) void gather_head_kernel(
    const ushort* __restrict__ msg16, const int* __restrict__ start,
    const float* __restrict__ r, const int* __restrict__ batch,
    float* __restrict__ sums, float* __restrict__ counts_f,
    const float* __restrict__ l1_w, const float* __restrict__ l1_b,
    const float* __restrict__ l2_w, const float* __restrict__ l2_b,
    float* __restrict__ out, int* __restrict__ done)
{
    const int wave = threadIdx.x >> 6;
    const int j    = threadIdx.x & 63;
    const int n0   = blockIdx.x * (4 * GN_PER_WAVE) + wave * GN_PER_WAVE;
    if (n0 < N_NODES) {
        const int n1 = min(n0 + GN_PER_WAVE, N_NODES);
        const float rj = r[j];

        int   g    = batch[n0];
        float pacc = 0.f, cnt = 0.f;
        for (int n = n0; n < n1; ++n) {
            const int gn = batch[n];
            if (gn != g) {
                unsafeAtomicAdd(&sums[g * HID + j], pacc);
                if (j == 0) unsafeAtomicAdd(&counts_f[g], cnt);
                g = gn; pacc = 0.f; cnt = 0.f;
            }
            float a0 = 0.f, a1 = 0.f;
            const int p0 = start[n], p1 = start[n + 1];
            int p = p0;
            for (; p + 2 <= p1; p += 2) {
                a0 += bf2f(msg16[(long)p * HID + j]);
                a1 += bf2f(msg16[(long)(p + 1) * HID + j]);
            }
            if (p < p1) a0 += bf2f(msg16[(long)p * HID + j]);
            pacc += fmaxf(a0 + a1 + rj, 0.f);
            cnt  += 1.f;
        }
        unsafeAtomicAdd(&sums[g * HID + j], pacc);
        if (j == 0) unsafeAtomicAdd(&counts_f[g], cnt);
    }

    // ---- last-block head ----
    __shared__ int s_last;
    __syncthreads();
    if (threadIdx.x == 0) {
        int prev = __hip_atomic_fetch_add(done, 1, __ATOMIC_ACQ_REL,
                                          __HIP_MEMORY_SCOPE_AGENT);
        s_last = (prev == (int)gridDim.x - 1);
    }
    __syncthreads();
    if (!s_last) return;

    __shared__ float pooled2[2][HID];
    __shared__ float hid2[2][2 * HID];
    const int half = threadIdx.x >> 7;        // which graph of the pair
    const int t    = threadIdx.x & 127;
    for (int g0 = 0; g0 < N_GRAPHS; g0 += 2) {
        const int g = g0 + half;
        __syncthreads();
        if (t < HID) {
            const float cnt = fmaxf(counts_f[g], 1.0f);
            pooled2[half][t] = sums[g * HID + t] / cnt;
        }
        __syncthreads();
        float a = l1_b[t];
#pragma unroll
        for (int k = 0; k < HID; ++k)
            a = fmaf(pooled2[half][k], l1_w[k * (2 * HID) + t], a);
        hid2[half][t] = fmaxf(a, 0.f);
        __syncthreads();
        if (t < OUT_DIM) {
            float o = l2_b[t];
#pragma unroll
            for (int k = 0; k < 2 * HID; ++k)
                o = fmaf(hid2[half][k], l2_w[k * OUT_DIM + t], o);
            out[g * OUT_DIM + t] = o;
        }
    }
}

// ---------------------------------------------------------------------------
extern "C" void kernel_launch(void* const* d_in, const int* in_sizes, int n_in,
                              void* d_out, int out_size, void* d_ws, size_t ws_size,
                              hipStream_t stream) {
    const float* edge_attr = (const float*)d_in[0];
    const int*   edge_idx  = (const int*)d_in[1];
    const int*   batch     = (const int*)d_in[2];
    const float* node_emb  = (const float*)d_in[3];
    const float* w1        = (const float*)d_in[4];
    const float* b1        = (const float*)d_in[5];
    const float* w2        = (const float*)d_in[6];
    const float* b2        = (const float*)d_in[7];
    const float* w3        = (const float*)d_in[8];
    const float* b3        = (const float*)d_in[9];
    const float* root_w    = (const float*)d_in[10];
    const float* conv_b    = (const float*)d_in[11];
    const float* l1_w      = (const float*)d_in[12];
    const float* l1_b      = (const float*)d_in[13];
    const float* l2_w      = (const float*)d_in[14];
    const float* l2_b      = (const float*)d_in[15];
    float* out = (float*)d_out;

    // workspace layout
    float* ws     = (float*)d_ws;
    float* W3p    = ws;                          // 4096
    float* b3p    = W3p + HID * HID;             // 64
    float* r      = b3p + HID;                   // 64
    float* sums   = r + HID;                     // 128*64
    float* cts    = sums + N_GRAPHS * HID;       // 128
    int*   counts = (int*)(cts + N_GRAPHS);      // 20000
    int*   done   = counts + N_NODES;            // 1 (zeroed with counts)
    int*   startp = done + 1;                    // 20001
    int*   cursor = startp + (N_NODES + 1);      // 20000
    int*   tot    = cursor + N_NODES;            // 20
    ushort* fw1 = (ushort*)(((uintptr_t)(tot + SCAN_NBLK) + 15) & ~(uintptr_t)15);
    ushort* fw2 = fw1 + 4096;                    // 8 frags  * 512
    ushort* fw3 = fw2 + 8192;                    // 16 frags * 512
    ushort* msg16 = fw3 + 8192;                  // 200000*64 ushorts (25.6 MB)

    // zero sums/cts/counts/done (contiguous region)
    hipMemsetAsync(sums, 0,
                   (size_t)(N_GRAPHS * HID + N_GRAPHS + N_NODES + 1) * 4, stream);

    const int* dst_idx = edge_idx + N_EDGES;   // edge_index[1]

    combo_kernel<<<64 + (N_EDGES + 255) / 256, 256, 0, stream>>>(
        node_emb, w3, b3, root_w, conv_b, dst_idx, w1, w2,
        W3p, b3p, r, fw1, fw2, counts);

    scanA_kernel<<<SCAN_NBLK + 8, 1024, 0, stream>>>(counts, startp, tot, W3p, fw3);
    scanC_kernel<<<SCAN_NBLK, 1024, 0, stream>>>(startp, cursor, tot);

    edge_mfma_kernel<<<(N_EWAVES + 3) / 4, 256, 0, stream>>>(
        edge_attr, dst_idx, fw1, fw2, fw3, b1, b2, b3p, cursor, msg16);

    gather_head_kernel<<<(N_NODES + 4 * GN_PER_WAVE - 1) / (4 * GN_PER_WAVE), 256, 0, stream>>>(
        msg16, startp, r, batch, sums, cts, l1_w, l1_b, l2_w, l2_b, out, done);
}

// Round 23
// 85.204 us; speedup vs baseline: 5.9120x; 5.9120x over previous
//
#include <hip/hip_runtime.h>
#include <hip/hip_bf16.h>
#include <hip/amd_detail/amd_hip_unsafe_atomics.h>

#define N_EDGES 200000
#define N_NODES 20000
#define N_GRAPHS 128
#define IN_DIM 16
#define EDGE_DIM 8
#define HID 64
#define OUT_DIM 10
#define SCAN_NBLK ((N_NODES + 1023) / 1024)   // 20
#define N_TILES (N_EDGES / 16)                // 12500 tiles of 16 edges
#define TPW 1                                 // tiles per wave (isolated change vs R18)
#define N_EWAVES (N_TILES / TPW)              // 12500

typedef __attribute__((ext_vector_type(8))) short bf16x8;
typedef __attribute__((ext_vector_type(4))) float f32x4;

__device__ __forceinline__ ushort f2bf(float x) {
    unsigned b = __float_as_uint(x);
    return (ushort)((b + 0x7FFFu + ((b >> 16) & 1u)) >> 16);
}
__device__ __forceinline__ float bf2f(ushort u) {
    return __uint_as_float(((unsigned)u) << 16);
}

// ---------------------------------------------------------------------------
// Kernel A (combo): blocks 0..15  = precompute W3p/b3p/r,
//                   blocks 16..63 = pack w1,w2 into MFMA B-frag bf16 hi/lo,
//                   blocks 64..   = histogram of dst.
// ---------------------------------------------------------------------------
__global__ __launch_bounds__(256) void combo_kernel(
    const float* __restrict__ emb, const float* __restrict__ w3,
    const float* __restrict__ b3, const float* __restrict__ root_w,
    const float* __restrict__ conv_b, const int* __restrict__ dst_idx,
    const float* __restrict__ w1, const float* __restrict__ w2,
    float* __restrict__ W3p, float* __restrict__ b3p, float* __restrict__ r,
    ushort* __restrict__ fw1, ushort* __restrict__ fw2,
    int* __restrict__ counts)
{
    if (blockIdx.x < 16) {
        int t = blockIdx.x * 256 + threadIdx.x;   // 0..4095
        int k = t >> 6;
        int h = t & 63;
        float acc = 0.f;
#pragma unroll
        for (int i = 0; i < IN_DIM; ++i)
            acc = fmaf(emb[i], w3[k * (IN_DIM * HID) + i * HID + h], acc);
        W3p[t] = acc;
        if (t < HID) {
            float a = 0.f, rr = 0.f;
#pragma unroll
            for (int i = 0; i < IN_DIM; ++i) {
                a  = fmaf(emb[i], b3[i * HID + t], a);
                rr = fmaf(emb[i], root_w[i * HID + t], rr);
            }
            b3p[t] = a;
            r[t]   = rr + conv_b[t];
        }
    } else if (blockIdx.x < 64) {
        int idx  = (blockIdx.x - 16) * 256 + threadIdx.x;  // 0..12287
        int frag = idx >> 9;
        int rem  = idx & 511;
        int lane = rem >> 3, i = rem & 7;
        int q = lane >> 4, n16 = lane & 15;
        if (frag < 8) {
            int t = frag >> 1, h = frag & 1;
            int k = 8 * q + i, n = t * 16 + n16;
            float v = (k < EDGE_DIM) ? w1[k * HID + n] : 0.f;
            ushort hi = f2bf(v);
            fw1[((t * 2 + h) * 64 + lane) * 8 + i] =
                (h == 0) ? hi : f2bf(v - bf2f(hi));
        } else {
            int u = frag - 8;
            int t = u >> 2, f = (u >> 1) & 1, h = u & 1;
            int k = f * 32 + 8 * q + i, n = t * 16 + n16;
            float v = w2[k * HID + n];
            ushort hi = f2bf(v);
            fw2[(((t * 2 + f) * 2 + h) * 64 + lane) * 8 + i] =
                (h == 0) ? hi : f2bf(v - bf2f(hi));
        }
    } else {
        int e = (blockIdx.x - 64) * 256 + threadIdx.x;
        if (e < N_EDGES) atomicAdd(&counts[dst_idx[e]], 1);
    }
}

// ---------------------------------------------------------------------------
// scanA: block-local scan (+ extra blocks pack W3p frags).
// ---------------------------------------------------------------------------
__global__ __launch_bounds__(1024) void scanA_kernel(
    const int* __restrict__ counts, int* __restrict__ start, int* __restrict__ tot,
    const float* __restrict__ W3p, ushort* __restrict__ fw3)
{
    const int b = blockIdx.x, t = threadIdx.x;
    if (b >= SCAN_NBLK) {                       // blocks 20..27: fw3 prep
        int idx  = (b - SCAN_NBLK) * 1024 + t;  // 0..8191
        int u    = idx >> 9;
        int rem  = idx & 511;
        int lane = rem >> 3, i = rem & 7;
        int tt = u >> 2, f = (u >> 1) & 1, h = u & 1;
        int k = f * 32 + 8 * (lane >> 4) + i, n = tt * 16 + (lane & 15);
        float v = W3p[k * HID + n];
        ushort hi = f2bf(v);
        fw3[(((tt * 2 + f) * 2 + h) * 64 + lane) * 8 + i] =
            (h == 0) ? hi : f2bf(v - bf2f(hi));
        return;
    }
    const int i = b * 1024 + t;
    const int v = (i < N_NODES) ? counts[i] : 0;
    const int lane = t & 63, wid = t >> 6;
    __shared__ int wsum[16];
    int incl = v;
#pragma unroll
    for (int off = 1; off < 64; off <<= 1) {
        int u = __shfl_up(incl, off, 64);
        if (lane >= off) incl += u;
    }
    if (lane == 63) wsum[wid] = incl;
    __syncthreads();
    if (wid == 0) {
        int wv = (lane < 16) ? wsum[lane] : 0;
        int wi = wv;
#pragma unroll
        for (int off = 1; off < 16; off <<= 1) {
            int u = __shfl_up(wi, off, 64);
            if (lane >= off) wi += u;
        }
        if (lane < 16) wsum[lane] = wi - wv;
    }
    __syncthreads();
    const int excl = wsum[wid] + incl - v;
    if (i < N_NODES) start[i] = excl;
    if (t == 1023) tot[b] = excl + v;
}

// ---------------------------------------------------------------------------
// scanC: block b sums tot[0..b-1] with a wave reduce, then applies offset.
// ---------------------------------------------------------------------------
__global__ __launch_bounds__(1024) void scanC_kernel(
    int* __restrict__ start, int* __restrict__ cursor, const int* __restrict__ tot)
{
    __shared__ int s_off;
    const int b = blockIdx.x, t = threadIdx.x;
    if (t < 64) {
        int v = (t < b && t < SCAN_NBLK) ? tot[t] : 0;
#pragma unroll
        for (int o = 32; o >= 1; o >>= 1) v += __shfl_xor(v, o, 64);
        if (t == 0) s_off = v;
    }
    __syncthreads();
    const int i = b * 1024 + t;
    if (i < N_NODES) {
        const int s = start[i] + s_off;
        start[i]  = s;
        cursor[i] = s;
    }
    if (b == 0 && t == 0) start[N_NODES] = N_EDGES;
}

// ---------------------------------------------------------------------------
// Kernel D: edge MLP on matrix cores, split-bf16 (verified: absmax 3e-5).
// TPW=1: 18.4 KB LDS/block -> 8 blocks/CU for latency hiding.
// ---------------------------------------------------------------------------
__global__ __launch_bounds__(256) void edge_mfma_kernel(
    const float* __restrict__ edge_attr, const int* __restrict__ dst_idx,
    const ushort* __restrict__ fw1, const ushort* __restrict__ fw2,
    const ushort* __restrict__ fw3,
    const float* __restrict__ b1, const float* __restrict__ b2,
    const float* __restrict__ b3p,
    int* __restrict__ cursor, ushort* __restrict__ msg16)
{
    const int lane = threadIdx.x & 63;
    const int wv   = threadIdx.x >> 6;
    const int gw   = blockIdx.x * 4 + wv;
    const int tile0 = gw * TPW;
    if (tile0 >= N_TILES) return;
    const int q = lane >> 4, l16 = lane & 15;

    __shared__ ushort s_hi[4][TPW][16][72];
    __shared__ ushort s_lo[4][TPW][16][72];

    float bb1[4], bb2[4], bb3[4];
#pragma unroll
    for (int t = 0; t < 4; ++t) {
        bb1[t] = b1[t * 16 + l16];
        bb2[t] = b2[t * 16 + l16];
        bb3[t] = b3p[t * 16 + l16];
    }

    float e8[TPW][8];
    int   p_mine[TPW];
#pragma unroll
    for (int tt = 0; tt < TPW; ++tt) {
        p_mine[tt] = 0;
#pragma unroll
        for (int i = 0; i < 8; ++i) e8[tt][i] = 0.f;
        if (lane < 16) {
            const long em = (long)(tile0 + tt) * 16 + lane;
            const float4 A = *(const float4*)&edge_attr[em * EDGE_DIM + 0];
            const float4 B = *(const float4*)&edge_attr[em * EDGE_DIM + 4];
            e8[tt][0] = A.x; e8[tt][1] = A.y; e8[tt][2] = A.z; e8[tt][3] = A.w;
            e8[tt][4] = B.x; e8[tt][5] = B.y; e8[tt][6] = B.z; e8[tt][7] = B.w;
            p_mine[tt] = atomicAdd(&cursor[dst_idx[em]], 1);
        }
    }

    // ---- phase 1: L1 (K=8 zero-padded) ----
    {
        bf16x8 w1h[4], w1l[4];
#pragma unroll
        for (int t = 0; t < 4; ++t) {
            w1h[t] = ((const bf16x8*)fw1)[(t * 2 + 0) * 64 + lane];
            w1l[t] = ((const bf16x8*)fw1)[(t * 2 + 1) * 64 + lane];
        }
#pragma unroll
        for (int tt = 0; tt < TPW; ++tt) {
            bf16x8 a1h, a1l;
#pragma unroll
            for (int i = 0; i < 8; ++i) {
                const ushort hi = f2bf(e8[tt][i]);
                a1h[i] = (short)hi;
                a1l[i] = (short)f2bf(e8[tt][i] - bf2f(hi));
            }
#pragma unroll
            for (int t = 0; t < 4; ++t) {
                f32x4 c = {0.f, 0.f, 0.f, 0.f};
                c = __builtin_amdgcn_mfma_f32_16x16x32_bf16(a1l, w1h[t], c, 0, 0, 0);
                c = __builtin_amdgcn_mfma_f32_16x16x32_bf16(a1h, w1l[t], c, 0, 0, 0);
                c = __builtin_amdgcn_mfma_f32_16x16x32_bf16(a1h, w1h[t], c, 0, 0, 0);
#pragma unroll
                for (int rr = 0; rr < 4; ++rr) {
                    float x = fmaxf(c[rr] + bb1[t], 0.f);
                    const ushort hi = f2bf(x);
                    s_hi[wv][tt][q * 4 + rr][t * 16 + l16] = hi;
                    s_lo[wv][tt][q * 4 + rr][t * 16 + l16] = f2bf(x - bf2f(hi));
                }
            }
        }
    }

    // ---- phase 2: L2 (K=64) ----
    {
        bf16x8 w2h[4][2], w2l[4][2];
#pragma unroll
        for (int t = 0; t < 4; ++t)
#pragma unroll
            for (int f = 0; f < 2; ++f) {
                w2h[t][f] = ((const bf16x8*)fw2)[((t * 2 + f) * 2 + 0) * 64 + lane];
                w2l[t][f] = ((const bf16x8*)fw2)[((t * 2 + f) * 2 + 1) * 64 + lane];
            }
#pragma unroll
        for (int tt = 0; tt < TPW; ++tt) {
            bf16x8 a2h[2], a2l[2];
#pragma unroll
            for (int f = 0; f < 2; ++f) {
                a2h[f] = *(const bf16x8*)&s_hi[wv][tt][l16][f * 32 + 8 * q];
                a2l[f] = *(const bf16x8*)&s_lo[wv][tt][l16][f * 32 + 8 * q];
            }
            f32x4 cc[4];
#pragma unroll
            for (int t = 0; t < 4; ++t) {
                f32x4 c = {0.f, 0.f, 0.f, 0.f};
#pragma unroll
                for (int f = 0; f < 2; ++f) {
                    c = __builtin_amdgcn_mfma_f32_16x16x32_bf16(a2l[f], w2h[t][f], c, 0, 0, 0);
                    c = __builtin_amdgcn_mfma_f32_16x16x32_bf16(a2h[f], w2l[t][f], c, 0, 0, 0);
                    c = __builtin_amdgcn_mfma_f32_16x16x32_bf16(a2h[f], w2h[t][f], c, 0, 0, 0);
                }
                cc[t] = c;
            }
#pragma unroll
            for (int t = 0; t < 4; ++t)
#pragma unroll
                for (int rr = 0; rr < 4; ++rr) {
                    float x = fmaxf(cc[t][rr] + bb2[t], 0.f);
                    const ushort hi = f2bf(x);
                    s_hi[wv][tt][q * 4 + rr][t * 16 + l16] = hi;
                    s_lo[wv][tt][q * 4 + rr][t * 16 + l16] = f2bf(x - bf2f(hi));
                }
        }
    }

    // ---- phase 3: L3 (K=64) + bf16 store ----
    {
        bf16x8 w3h[4][2], w3l[4][2];
#pragma unroll
        for (int t = 0; t < 4; ++t)
#pragma unroll
            for (int f = 0; f < 2; ++f) {
                w3h[t][f] = ((const bf16x8*)fw3)[((t * 2 + f) * 2 + 0) * 64 + lane];
                w3l[t][f] = ((const bf16x8*)fw3)[((t * 2 + f) * 2 + 1) * 64 + lane];
            }
#pragma unroll
        for (int tt = 0; tt < TPW; ++tt) {
            bf16x8 a3h[2], a3l[2];
#pragma unroll
            for (int f = 0; f < 2; ++f) {
                a3h[f] = *(const bf16x8*)&s_hi[wv][tt][l16][f * 32 + 8 * q];
                a3l[f] = *(const bf16x8*)&s_lo[wv][tt][l16][f * 32 + 8 * q];
            }
            f32x4 cc[4];
#pragma unroll
            for (int t = 0; t < 4; ++t) {
                f32x4 c = {0.f, 0.f, 0.f, 0.f};
#pragma unroll
                for (int f = 0; f < 2; ++f) {
                    c = __builtin_amdgcn_mfma_f32_16x16x32_bf16(a3l[f], w3h[t][f], c, 0, 0, 0);
                    c = __builtin_amdgcn_mfma_f32_16x16x32_bf16(a3h[f], w3l[t][f], c, 0, 0, 0);
                    c = __builtin_amdgcn_mfma_f32_16x16x32_bf16(a3h[f], w3h[t][f], c, 0, 0, 0);
                }
                cc[t] = c;
            }
            int p_r[4];
#pragma unroll
            for (int rr = 0; rr < 4; ++rr)
                p_r[rr] = __shfl(p_mine[tt], q * 4 + rr);
#pragma unroll
            for (int t = 0; t < 4; ++t)
#pragma unroll
                for (int rr = 0; rr < 4; ++rr)
                    msg16[(long)p_r[rr] * HID + t * 16 + l16] =
                        f2bf(cc[t][rr] + bb3[t]);
        }
    }
}

// ---------------------------------------------------------------------------
// Kernel E: gather bf16 msg rows per node, +r, relu, pooled sums/counts.
// GN_PER_WAVE=8 (measured best); p-loop 2-way pipelined (independent accs).
// ---------------------------------------------------------------------------
#define GN_PER_WAVE 8
__global__ __launch_bounds__(256) void gather_kernel(
    const ushort* __restrict__ msg16, const int* __restrict__ start,
    const float* __restrict__ r, const int* __restrict__ batch,
    float* __restrict__ sums, float* __restrict__ counts_f)
{
    const int wave = threadIdx.x >> 6;
    const int j    = threadIdx.x & 63;
    const int n0   = blockIdx.x * (4 * GN_PER_WAVE) + wave * GN_PER_WAVE;
    if (n0 >= N_NODES) return;
    const int n1 = min(n0 + GN_PER_WAVE, N_NODES);
    const float rj = r[j];

    int   g    = batch[n0];
    float pacc = 0.f, cnt = 0.f;
    for (int n = n0; n < n1; ++n) {
        const int gn = batch[n];
        if (gn != g) {
            unsafeAtomicAdd(&sums[g * HID + j], pacc);
            if (j == 0) unsafeAtomicAdd(&counts_f[g], cnt);
            g = gn; pacc = 0.f; cnt = 0.f;
        }
        float a0 = 0.f, a1 = 0.f;
        const int p0 = start[n], p1 = start[n + 1];
        int p = p0;
        for (; p + 2 <= p1; p += 2) {
            a0 += bf2f(msg16[(long)p * HID + j]);
            a1 += bf2f(msg16[(long)(p + 1) * HID + j]);
        }
        if (p < p1) a0 += bf2f(msg16[(long)p * HID + j]);
        pacc += fmaxf(a0 + a1 + rj, 0.f);
        cnt  += 1.f;
    }
    unsafeAtomicAdd(&sums[g * HID + j], pacc);
    if (j == 0) unsafeAtomicAdd(&counts_f[g], cnt);
}

// ---------------------------------------------------------------------------
// Kernel F: classifier head. One block (128 threads) per graph.
// ---------------------------------------------------------------------------
__global__ __launch_bounds__(128) void head_kernel(
    const float* __restrict__ sums, const float* __restrict__ counts,
    const float* __restrict__ l1_w, const float* __restrict__ l1_b,
    const float* __restrict__ l2_w, const float* __restrict__ l2_b,
    float* __restrict__ out)
{
    const int g = blockIdx.x;
    const int t = threadIdx.x;
    __shared__ float pooled[HID];
    __shared__ float hid[2 * HID];

    const float cnt = fmaxf(counts[g], 1.0f);
    if (t < HID) pooled[t] = sums[g * HID + t] / cnt;
    __syncthreads();

    float a = l1_b[t];
#pragma unroll
    for (int k = 0; k < HID; ++k)
        a = fmaf(pooled[k], l1_w[k * (2 * HID) + t], a);
    hid[t] = fmaxf(a, 0.f);
    __syncthreads();

    if (t < OUT_DIM) {
        float o = l2_b[t];
#pragma unroll
        for (int k = 0; k < 2 * HID; ++k)
            o = fmaf(hid[k], l2_w[k * OUT_DIM + t], o);
        out[g * OUT_DIM + t] = o;
    }
}

// ---------------------------------------------------------------------------
extern "C" void kernel_launch(void* const* d_in, const int* in_sizes, int n_in,
                              void* d_out, int out_size, void* d_ws, size_t ws_size,
                              hipStream_t stream) {
    const float* edge_attr = (const float*)d_in[0];
    const int*   edge_idx  = (const int*)d_in[1];
    const int*   batch     = (const int*)d_in[2];
    const float* node_emb  = (const float*)d_in[3];
    const float* w1        = (const float*)d_in[4];
    const float* b1        = (const float*)d_in[5];
    const float* w2        = (const float*)d_in[6];
    const float* b2        = (const float*)d_in[7];
    const float* w3        = (const float*)d_in[8];
    const float* b3        = (const float*)d_in[9];
    const float* root_w    = (const float*)d_in[10];
    const float* conv_b    = (const float*)d_in[11];
    const float* l1_w      = (const float*)d_in[12];
    const float* l1_b      = (const float*)d_in[13];
    const float* l2_w      = (const float*)d_in[14];
    const float* l2_b      = (const float*)d_in[15];
    float* out = (float*)d_out;

    // workspace layout
    float* ws     = (float*)d_ws;
    float* W3p    = ws;                          // 4096
    float* b3p    = W3p + HID * HID;             // 64
    float* r      = b3p + HID;                   // 64
    float* sums   = r + HID;                     // 128*64
    float* cts    = sums + N_GRAPHS * HID;       // 128
    int*   counts = (int*)(cts + N_GRAPHS);      // 20000
    int*   startp = counts + N_NODES;            // 20001
    int*   cursor = startp + (N_NODES + 1);      // 20000
    int*   tot    = cursor + N_NODES;            // 20
    ushort* fw1 = (ushort*)(((uintptr_t)(tot + SCAN_NBLK) + 15) & ~(uintptr_t)15);
    ushort* fw2 = fw1 + 4096;                    // 8 frags  * 512
    ushort* fw3 = fw2 + 8192;                    // 16 frags * 512
    ushort* msg16 = fw3 + 8192;                  // 200000*64 ushorts (25.6 MB)

    // zero sums/cts/counts (contiguous region)
    hipMemsetAsync(sums, 0,
                   (size_t)(N_GRAPHS * HID + N_GRAPHS + N_NODES) * 4, stream);

    const int* dst_idx = edge_idx + N_EDGES;   // edge_index[1]

    combo_kernel<<<64 + (N_EDGES + 255) / 256, 256, 0, stream>>>(
        node_emb, w3, b3, root_w, conv_b, dst_idx, w1, w2,
        W3p, b3p, r, fw1, fw2, counts);

    scanA_kernel<<<SCAN_NBLK + 8, 1024, 0, stream>>>(counts, startp, tot, W3p, fw3);
    scanC_kernel<<<SCAN_NBLK, 1024, 0, stream>>>(startp, cursor, tot);

    edge_mfma_kernel<<<(N_EWAVES + 3) / 4, 256, 0, stream>>>(
        edge_attr, dst_idx, fw1, fw2, fw3, b1, b2, b3p, cursor, msg16);

    gather_kernel<<<(N_NODES + 4 * GN_PER_WAVE - 1) / (4 * GN_PER_WAVE), 256, 0, stream>>>(
        msg16, startp, r, batch, sums, cts);

    head_kernel<<<N_GRAPHS, 128, 0, stream>>>(
        sums, cts, l1_w, l1_b, l2_w, l2_b, out);
}

// Round 24
// 83.047 us; speedup vs baseline: 6.0656x; 1.0260x over previous
//
#include <hip/hip_runtime.h>
#include <hip/hip_bf16.h>
#include <hip/amd_detail/amd_hip_unsafe_atomics.h>

#define N_EDGES 200000
#define N_NODES 20000
#define N_GRAPHS 128
#define IN_DIM 16
#define EDGE_DIM 8
#define HID 64
#define OUT_DIM 10
#define SCAN_NBLK ((N_NODES + 1023) / 1024)   // 20
#define N_TILES (N_EDGES / 16)                // 12500 tiles of 16 edges
#define TPW 2                                 // tiles per wave (measured best: R18)
#define N_EWAVES (N_TILES / TPW)              // 6250

typedef __attribute__((ext_vector_type(8))) short bf16x8;
typedef __attribute__((ext_vector_type(4))) float f32x4;

__device__ __forceinline__ ushort f2bf(float x) {
    unsigned b = __float_as_uint(x);
    return (ushort)((b + 0x7FFFu + ((b >> 16) & 1u)) >> 16);
}
__device__ __forceinline__ float bf2f(ushort u) {
    return __uint_as_float(((unsigned)u) << 16);
}

// ---------------------------------------------------------------------------
// Kernel A (combo): blocks 0..15  = precompute W3p/b3p/r,
//                   blocks 16..63 = pack w1,w2 into MFMA B-frag bf16 hi/lo,
//                   blocks 64..   = histogram of dst.
// ---------------------------------------------------------------------------
__global__ __launch_bounds__(256) void combo_kernel(
    const float* __restrict__ emb, const float* __restrict__ w3,
    const float* __restrict__ b3, const float* __restrict__ root_w,
    const float* __restrict__ conv_b, const int* __restrict__ dst_idx,
    const float* __restrict__ w1, const float* __restrict__ w2,
    float* __restrict__ W3p, float* __restrict__ b3p, float* __restrict__ r,
    ushort* __restrict__ fw1, ushort* __restrict__ fw2,
    int* __restrict__ counts)
{
    if (blockIdx.x < 16) {
        int t = blockIdx.x * 256 + threadIdx.x;   // 0..4095
        int k = t >> 6;
        int h = t & 63;
        float acc = 0.f;
#pragma unroll
        for (int i = 0; i < IN_DIM; ++i)
            acc = fmaf(emb[i], w3[k * (IN_DIM * HID) + i * HID + h], acc);
        W3p[t] = acc;
        if (t < HID) {
            float a = 0.f, rr = 0.f;
#pragma unroll
            for (int i = 0; i < IN_DIM; ++i) {
                a  = fmaf(emb[i], b3[i * HID + t], a);
                rr = fmaf(emb[i], root_w[i * HID + t], rr);
            }
            b3p[t] = a;
            r[t]   = rr + conv_b[t];
        }
    } else if (blockIdx.x < 64) {
        int idx  = (blockIdx.x - 16) * 256 + threadIdx.x;  // 0..12287
        int frag = idx >> 9;
        int rem  = idx & 511;
        int lane = rem >> 3, i = rem & 7;
        int q = lane >> 4, n16 = lane & 15;
        if (frag < 8) {
            int t = frag >> 1, h = frag & 1;
            int k = 8 * q + i, n = t * 16 + n16;
            float v = (k < EDGE_DIM) ? w1[k * HID + n] : 0.f;
            ushort hi = f2bf(v);
            fw1[((t * 2 + h) * 64 + lane) * 8 + i] =
                (h == 0) ? hi : f2bf(v - bf2f(hi));
        } else {
            int u = frag - 8;
            int t = u >> 2, f = (u >> 1) & 1, h = u & 1;
            int k = f * 32 + 8 * q + i, n = t * 16 + n16;
            float v = w2[k * HID + n];
            ushort hi = f2bf(v);
            fw2[(((t * 2 + f) * 2 + h) * 64 + lane) * 8 + i] =
                (h == 0) ? hi : f2bf(v - bf2f(hi));
        }
    } else {
        int e = (blockIdx.x - 64) * 256 + threadIdx.x;
        if (e < N_EDGES) atomicAdd(&counts[dst_idx[e]], 1);
    }
}

// ---------------------------------------------------------------------------
// scanA: block-local scan (+ extra blocks pack W3p frags).
// ---------------------------------------------------------------------------
__global__ __launch_bounds__(1024) void scanA_kernel(
    const int* __restrict__ counts, int* __restrict__ start, int* __restrict__ tot,
    const float* __restrict__ W3p, ushort* __restrict__ fw3)
{
    const int b = blockIdx.x, t = threadIdx.x;
    if (b >= SCAN_NBLK) {                       // blocks 20..27: fw3 prep
        int idx  = (b - SCAN_NBLK) * 1024 + t;  // 0..8191
        int u    = idx >> 9;
        int rem  = idx & 511;
        int lane = rem >> 3, i = rem & 7;
        int tt = u >> 2, f = (u >> 1) & 1, h = u & 1;
        int k = f * 32 + 8 * (lane >> 4) + i, n = tt * 16 + (lane & 15);
        float v = W3p[k * HID + n];
        ushort hi = f2bf(v);
        fw3[(((tt * 2 + f) * 2 + h) * 64 + lane) * 8 + i] =
            (h == 0) ? hi : f2bf(v - bf2f(hi));
        return;
    }
    const int i = b * 1024 + t;
    const int v = (i < N_NODES) ? counts[i] : 0;
    const int lane = t & 63, wid = t >> 6;
    __shared__ int wsum[16];
    int incl = v;
#pragma unroll
    for (int off = 1; off < 64; off <<= 1) {
        int u = __shfl_up(incl, off, 64);
        if (lane >= off) incl += u;
    }
    if (lane == 63) wsum[wid] = incl;
    __syncthreads();
    if (wid == 0) {
        int wv = (lane < 16) ? wsum[lane] : 0;
        int wi = wv;
#pragma unroll
        for (int off = 1; off < 16; off <<= 1) {
            int u = __shfl_up(wi, off, 64);
            if (lane >= off) wi += u;
        }
        if (lane < 16) wsum[lane] = wi - wv;
    }
    __syncthreads();
    const int excl = wsum[wid] + incl - v;
    if (i < N_NODES) start[i] = excl;
    if (t == 1023) tot[b] = excl + v;
}

// ---------------------------------------------------------------------------
// scanC: block b sums tot[0..b-1] with a wave reduce, then applies offset.
// ---------------------------------------------------------------------------
__global__ __launch_bounds__(1024) void scanC_kernel(
    int* __restrict__ start, int* __restrict__ cursor, const int* __restrict__ tot)
{
    __shared__ int s_off;
    const int b = blockIdx.x, t = threadIdx.x;
    if (t < 64) {
        int v = (t < b && t < SCAN_NBLK) ? tot[t] : 0;
#pragma unroll
        for (int o = 32; o >= 1; o >>= 1) v += __shfl_xor(v, o, 64);
        if (t == 0) s_off = v;
    }
    __syncthreads();
    const int i = b * 1024 + t;
    if (i < N_NODES) {
        const int s = start[i] + s_off;
        start[i]  = s;
        cursor[i] = s;
    }
    if (b == 0 && t == 0) start[N_NODES] = N_EDGES;
}

// ---------------------------------------------------------------------------
// Kernel D: edge MLP on matrix cores, split-bf16 (verified: absmax 3e-5).
// TPW=2 (measured best: R18).
// ---------------------------------------------------------------------------
__global__ __launch_bounds__(256) void edge_mfma_kernel(
    const float* __restrict__ edge_attr, const int* __restrict__ dst_idx,
    const ushort* __restrict__ fw1, const ushort* __restrict__ fw2,
    const ushort* __restrict__ fw3,
    const float* __restrict__ b1, const float* __restrict__ b2,
    const float* __restrict__ b3p,
    int* __restrict__ cursor, ushort* __restrict__ msg16)
{
    const int lane = threadIdx.x & 63;
    const int wv   = threadIdx.x >> 6;
    const int gw   = blockIdx.x * 4 + wv;
    const int tile0 = gw * TPW;
    if (tile0 >= N_TILES) return;
    const int q = lane >> 4, l16 = lane & 15;

    __shared__ ushort s_hi[4][TPW][16][72];
    __shared__ ushort s_lo[4][TPW][16][72];

    float bb1[4], bb2[4], bb3[4];
#pragma unroll
    for (int t = 0; t < 4; ++t) {
        bb1[t] = b1[t * 16 + l16];
        bb2[t] = b2[t * 16 + l16];
        bb3[t] = b3p[t * 16 + l16];
    }

    float e8[TPW][8];
    int   p_mine[TPW];
#pragma unroll
    for (int tt = 0; tt < TPW; ++tt) {
        p_mine[tt] = 0;
#pragma unroll
        for (int i = 0; i < 8; ++i) e8[tt][i] = 0.f;
        if (lane < 16) {
            const long em = (long)(tile0 + tt) * 16 + lane;
            const float4 A = *(const float4*)&edge_attr[em * EDGE_DIM + 0];
            const float4 B = *(const float4*)&edge_attr[em * EDGE_DIM + 4];
            e8[tt][0] = A.x; e8[tt][1] = A.y; e8[tt][2] = A.z; e8[tt][3] = A.w;
            e8[tt][4] = B.x; e8[tt][5] = B.y; e8[tt][6] = B.z; e8[tt][7] = B.w;
            p_mine[tt] = atomicAdd(&cursor[dst_idx[em]], 1);
        }
    }

    // ---- phase 1: L1 (K=8 zero-padded) ----
    {
        bf16x8 w1h[4], w1l[4];
#pragma unroll
        for (int t = 0; t < 4; ++t) {
            w1h[t] = ((const bf16x8*)fw1)[(t * 2 + 0) * 64 + lane];
            w1l[t] = ((const bf16x8*)fw1)[(t * 2 + 1) * 64 + lane];
        }
#pragma unroll
        for (int tt = 0; tt < TPW; ++tt) {
            bf16x8 a1h, a1l;
#pragma unroll
            for (int i = 0; i < 8; ++i) {
                const ushort hi = f2bf(e8[tt][i]);
                a1h[i] = (short)hi;
                a1l[i] = (short)f2bf(e8[tt][i] - bf2f(hi));
            }
#pragma unroll
            for (int t = 0; t < 4; ++t) {
                f32x4 c = {0.f, 0.f, 0.f, 0.f};
                c = __builtin_amdgcn_mfma_f32_16x16x32_bf16(a1l, w1h[t], c, 0, 0, 0);
                c = __builtin_amdgcn_mfma_f32_16x16x32_bf16(a1h, w1l[t], c, 0, 0, 0);
                c = __builtin_amdgcn_mfma_f32_16x16x32_bf16(a1h, w1h[t], c, 0, 0, 0);
#pragma unroll
                for (int rr = 0; rr < 4; ++rr) {
                    float x = fmaxf(c[rr] + bb1[t], 0.f);
                    const ushort hi = f2bf(x);
                    s_hi[wv][tt][q * 4 + rr][t * 16 + l16] = hi;
                    s_lo[wv][tt][q * 4 + rr][t * 16 + l16] = f2bf(x - bf2f(hi));
                }
            }
        }
    }

    // ---- phase 2: L2 (K=64) ----
    {
        bf16x8 w2h[4][2], w2l[4][2];
#pragma unroll
        for (int t = 0; t < 4; ++t)
#pragma unroll
            for (int f = 0; f < 2; ++f) {
                w2h[t][f] = ((const bf16x8*)fw2)[((t * 2 + f) * 2 + 0) * 64 + lane];
                w2l[t][f] = ((const bf16x8*)fw2)[((t * 2 + f) * 2 + 1) * 64 + lane];
            }
#pragma unroll
        for (int tt = 0; tt < TPW; ++tt) {
            bf16x8 a2h[2], a2l[2];
#pragma unroll
            for (int f = 0; f < 2; ++f) {
                a2h[f] = *(const bf16x8*)&s_hi[wv][tt][l16][f * 32 + 8 * q];
                a2l[f] = *(const bf16x8*)&s_lo[wv][tt][l16][f * 32 + 8 * q];
            }
            f32x4 cc[4];
#pragma unroll
            for (int t = 0; t < 4; ++t) {
                f32x4 c = {0.f, 0.f, 0.f, 0.f};
#pragma unroll
                for (int f = 0; f < 2; ++f) {
                    c = __builtin_amdgcn_mfma_f32_16x16x32_bf16(a2l[f], w2h[t][f], c, 0, 0, 0);
                    c = __builtin_amdgcn_mfma_f32_16x16x32_bf16(a2h[f], w2l[t][f], c, 0, 0, 0);
                    c = __builtin_amdgcn_mfma_f32_16x16x32_bf16(a2h[f], w2h[t][f], c, 0, 0, 0);
                }
                cc[t] = c;
            }
#pragma unroll
            for (int t = 0; t < 4; ++t)
#pragma unroll
                for (int rr = 0; rr < 4; ++rr) {
                    float x = fmaxf(cc[t][rr] + bb2[t], 0.f);
                    const ushort hi = f2bf(x);
                    s_hi[wv][tt][q * 4 + rr][t * 16 + l16] = hi;
                    s_lo[wv][tt][q * 4 + rr][t * 16 + l16] = f2bf(x - bf2f(hi));
                }
        }
    }

    // ---- phase 3: L3 (K=64) + bf16 store ----
    {
        bf16x8 w3h[4][2], w3l[4][2];
#pragma unroll
        for (int t = 0; t < 4; ++t)
#pragma unroll
            for (int f = 0; f < 2; ++f) {
                w3h[t][f] = ((const bf16x8*)fw3)[((t * 2 + f) * 2 + 0) * 64 + lane];
                w3l[t][f] = ((const bf16x8*)fw3)[((t * 2 + f) * 2 + 1) * 64 + lane];
            }
#pragma unroll
        for (int tt = 0; tt < TPW; ++tt) {
            bf16x8 a3h[2], a3l[2];
#pragma unroll
            for (int f = 0; f < 2; ++f) {
                a3h[f] = *(const bf16x8*)&s_hi[wv][tt][l16][f * 32 + 8 * q];
                a3l[f] = *(const bf16x8*)&s_lo[wv][tt][l16][f * 32 + 8 * q];
            }
            f32x4 cc[4];
#pragma unroll
            for (int t = 0; t < 4; ++t) {
                f32x4 c = {0.f, 0.f, 0.f, 0.f};
#pragma unroll
                for (int f = 0; f < 2; ++f) {
                    c = __builtin_amdgcn_mfma_f32_16x16x32_bf16(a3l[f], w3h[t][f], c, 0, 0, 0);
                    c = __builtin_amdgcn_mfma_f32_16x16x32_bf16(a3h[f], w3l[t][f], c, 0, 0, 0);
                    c = __builtin_amdgcn_mfma_f32_16x16x32_bf16(a3h[f], w3h[t][f], c, 0, 0, 0);
                }
                cc[t] = c;
            }
            int p_r[4];
#pragma unroll
            for (int rr = 0; rr < 4; ++rr)
                p_r[rr] = __shfl(p_mine[tt], q * 4 + rr);
#pragma unroll
            for (int t = 0; t < 4; ++t)
#pragma unroll
                for (int rr = 0; rr < 4; ++rr)
                    msg16[(long)p_r[rr] * HID + t * 16 + l16] =
                        f2bf(cc[t][rr] + bb3[t]);
        }
    }
}

// ---------------------------------------------------------------------------
// Kernel E: gather bf16 msg rows per node, +r, relu, pooled sums/counts.
// GN_PER_WAVE=8 (measured best); p-loop 2-way pipelined (independent accs).
// ---------------------------------------------------------------------------
#define GN_PER_WAVE 8
__global__ __launch_bounds__(256) void gather_kernel(
    const ushort* __restrict__ msg16, const int* __restrict__ start,
    const float* __restrict__ r, const int* __restrict__ batch,
    float* __restrict__ sums, float* __restrict__ counts_f)
{
    const int wave = threadIdx.x >> 6;
    const int j    = threadIdx.x & 63;
    const int n0   = blockIdx.x * (4 * GN_PER_WAVE) + wave * GN_PER_WAVE;
    if (n0 >= N_NODES) return;
    const int n1 = min(n0 + GN_PER_WAVE, N_NODES);
    const float rj = r[j];

    int   g    = batch[n0];
    float pacc = 0.f, cnt = 0.f;
    for (int n = n0; n < n1; ++n) {
        const int gn = batch[n];
        if (gn != g) {
            unsafeAtomicAdd(&sums[g * HID + j], pacc);
            if (j == 0) unsafeAtomicAdd(&counts_f[g], cnt);
            g = gn; pacc = 0.f; cnt = 0.f;
        }
        float a0 = 0.f, a1 = 0.f;
        const int p0 = start[n], p1 = start[n + 1];
        int p = p0;
        for (; p + 2 <= p1; p += 2) {
            a0 += bf2f(msg16[(long)p * HID + j]);
            a1 += bf2f(msg16[(long)(p + 1) * HID + j]);
        }
        if (p < p1) a0 += bf2f(msg16[(long)p * HID + j]);
        pacc += fmaxf(a0 + a1 + rj, 0.f);
        cnt  += 1.f;
    }
    unsafeAtomicAdd(&sums[g * HID + j], pacc);
    if (j == 0) unsafeAtomicAdd(&counts_f[g], cnt);
}

// ---------------------------------------------------------------------------
// Kernel F: classifier head. One block (128 threads) per graph.
// ---------------------------------------------------------------------------
__global__ __launch_bounds__(128) void head_kernel(
    const float* __restrict__ sums, const float* __restrict__ counts,
    const float* __restrict__ l1_w, const float* __restrict__ l1_b,
    const float* __restrict__ l2_w, const float* __restrict__ l2_b,
    float* __restrict__ out)
{
    const int g = blockIdx.x;
    const int t = threadIdx.x;
    __shared__ float pooled[HID];
    __shared__ float hid[2 * HID];

    const float cnt = fmaxf(counts[g], 1.0f);
    if (t < HID) pooled[t] = sums[g * HID + t] / cnt;
    __syncthreads();

    float a = l1_b[t];
#pragma unroll
    for (int k = 0; k < HID; ++k)
        a = fmaf(pooled[k], l1_w[k * (2 * HID) + t], a);
    hid[t] = fmaxf(a, 0.f);
    __syncthreads();

    if (t < OUT_DIM) {
        float o = l2_b[t];
#pragma unroll
        for (int k = 0; k < 2 * HID; ++k)
            o = fmaf(hid[k], l2_w[k * OUT_DIM + t], o);
        out[g * OUT_DIM + t] = o;
    }
}

// ---------------------------------------------------------------------------
extern "C" void kernel_launch(void* const* d_in, const int* in_sizes, int n_in,
                              void* d_out, int out_size, void* d_ws, size_t ws_size,
                              hipStream_t stream) {
    const float* edge_attr = (const float*)d_in[0];
    const int*   edge_idx  = (const int*)d_in[1];
    const int*   batch     = (const int*)d_in[2];
    const float* node_emb  = (const float*)d_in[3];
    const float* w1        = (const float*)d_in[4];
    const float* b1        = (const float*)d_in[5];
    const float* w2        = (const float*)d_in[6];
    const float* b2        = (const float*)d_in[7];
    const float* w3        = (const float*)d_in[8];
    const float* b3        = (const float*)d_in[9];
    const float* root_w    = (const float*)d_in[10];
    const float* conv_b    = (const float*)d_in[11];
    const float* l1_w      = (const float*)d_in[12];
    const float* l1_b      = (const float*)d_in[13];
    const float* l2_w      = (const float*)d_in[14];
    const float* l2_b      = (const float*)d_in[15];
    float* out = (float*)d_out;

    // workspace layout
    float* ws     = (float*)d_ws;
    float* W3p    = ws;                          // 4096
    float* b3p    = W3p + HID * HID;             // 64
    float* r      = b3p + HID;                   // 64
    float* sums   = r + HID;                     // 128*64
    float* cts    = sums + N_GRAPHS * HID;       // 128
    int*   counts = (int*)(cts + N_GRAPHS);      // 20000
    int*   startp = counts + N_NODES;            // 20001
    int*   cursor = startp + (N_NODES + 1);      // 20000
    int*   tot    = cursor + N_NODES;            // 20
    ushort* fw1 = (ushort*)(((uintptr_t)(tot + SCAN_NBLK) + 15) & ~(uintptr_t)15);
    ushort* fw2 = fw1 + 4096;                    // 8 frags  * 512
    ushort* fw3 = fw2 + 8192;                    // 16 frags * 512
    ushort* msg16 = fw3 + 8192;                  // 200000*64 ushorts (25.6 MB)

    // zero sums/cts/counts (contiguous region)
    hipMemsetAsync(sums, 0,
                   (size_t)(N_GRAPHS * HID + N_GRAPHS + N_NODES) * 4, stream);

    const int* dst_idx = edge_idx + N_EDGES;   // edge_index[1]

    combo_kernel<<<64 + (N_EDGES + 255) / 256, 256, 0, stream>>>(
        node_emb, w3, b3, root_w, conv_b, dst_idx, w1, w2,
        W3p, b3p, r, fw1, fw2, counts);

    scanA_kernel<<<SCAN_NBLK + 8, 1024, 0, stream>>>(counts, startp, tot, W3p, fw3);
    scanC_kernel<<<SCAN_NBLK, 1024, 0, stream>>>(startp, cursor, tot);

    edge_mfma_kernel<<<(N_EWAVES + 3) / 4, 256, 0, stream>>>(
        edge_attr, dst_idx, fw1, fw2, fw3, b1, b2, b3p, cursor, msg16);

    gather_kernel<<<(N_NODES + 4 * GN_PER_WAVE - 1) / (4 * GN_PER_WAVE), 256, 0, stream>>>(
        msg16, startp, r, batch, sums, cts);

    head_kernel<<<N_GRAPHS, 128, 0, stream>>>(
        sums, cts, l1_w, l1_b, l2_w, l2_b, out);
}